// Round 2
// baseline (15292.661 us; speedup 1.0000x reference)
//
#include <hip/hip_runtime.h>
#include <cstddef>
#include <cstdint>

#define T_LEN 4096
#define FDIM  1024
#define H2DIM 1024
#define GDIM  4096   // 4*H2

#define NEGV (-10000.0f)
#define START_TAG 2
#define STOP_TAG 3

// ---- workspace layout (bytes) ----
#define XP_OFF      ((size_t)0)
#define XP_BYTES    ((size_t)2 * T_LEN * GDIM * 4)          // 134,217,728
#define HIST_OFF    (XP_OFF + XP_BYTES)
#define HIST_BYTES  ((size_t)T_LEN * 2048 * 4)              // 33,554,432
#define FEATS_OFF   (HIST_OFF + HIST_BYTES)
#define FEATS_BYTES ((size_t)T_LEN * 4 * 4)
#define SLOTS_OFF   (FEATS_OFF + FEATS_BYTES)
#define SLOTS_BYTES ((size_t)2 * 2 * 1024 * 8)              // parity x dir x unit, u64
#define WS_NEED     (SLOTS_OFF + SLOTS_BYTES)

__device__ __forceinline__ float sigm(float x) { return 1.0f / (1.0f + expf(-x)); }

// ============================================================================
// Kernel 1: xp[dir][s][j] = dot(x[row(s)], w_ih_dir[j]) + b_ih[j] + b_hh[j]
// dir=0: row=s ; dir=1: row = 4095-s (backward scan order).
// 128x128 tile, BK=32, 256 threads, 8x8 microtile. fp32 (no fp32 MFMA).
// ============================================================================
__global__ __launch_bounds__(256)
void xp_gemm(const float* __restrict__ x,
             const float* __restrict__ w_f, const float* __restrict__ w_b,
             const float* __restrict__ bi_f, const float* __restrict__ bh_f,
             const float* __restrict__ bi_b, const float* __restrict__ bh_b,
             float* __restrict__ xp)
{
    const int tid = threadIdx.x;
    const int dir = blockIdx.z;
    const int j0  = blockIdx.x * 128;
    const int t0  = blockIdx.y * 128;
    const float* __restrict__ w  = dir ? w_b  : w_f;
    const float* __restrict__ bi = dir ? bi_b : bi_f;
    const float* __restrict__ bh = dir ? bh_b : bh_f;

    __shared__ float As[32][133];   // [k][m], padded
    __shared__ float Bs[32][133];   // [k][n]

    const int tm0 = (tid & 15) * 8;
    const int tn0 = (tid >> 4) * 8;

    float acc[8][8];
    #pragma unroll
    for (int i = 0; i < 8; ++i)
        #pragma unroll
        for (int j = 0; j < 8; ++j) acc[i][j] = 0.f;

    const int lrow = tid >> 3;        // 0..31
    const int lkq  = (tid & 7) * 4;   // 0..28

    for (int kb = 0; kb < FDIM; kb += 32) {
        #pragma unroll
        for (int hh = 0; hh < 4; ++hh) {
            const int r  = lrow + hh * 32;            // 0..127
            const int tg = t0 + r;
            const int sr = dir ? (T_LEN - 1 - tg) : tg;
            const float4 av = *(const float4*)&x[(size_t)sr * FDIM + kb + lkq];
            As[lkq+0][r] = av.x; As[lkq+1][r] = av.y; As[lkq+2][r] = av.z; As[lkq+3][r] = av.w;
            const float4 bv = *(const float4*)&w[(size_t)(j0 + r) * FDIM + kb + lkq];
            Bs[lkq+0][r] = bv.x; Bs[lkq+1][r] = bv.y; Bs[lkq+2][r] = bv.z; Bs[lkq+3][r] = bv.w;
        }
        __syncthreads();
        #pragma unroll
        for (int k = 0; k < 32; ++k) {
            const float4 a0 = *(const float4*)&As[k][tm0];
            const float4 a1 = *(const float4*)&As[k][tm0 + 4];
            const float4 b0 = *(const float4*)&Bs[k][tn0];
            const float4 b1 = *(const float4*)&Bs[k][tn0 + 4];
            const float av[8] = {a0.x,a0.y,a0.z,a0.w,a1.x,a1.y,a1.z,a1.w};
            const float bv[8] = {b0.x,b0.y,b0.z,b0.w,b1.x,b1.y,b1.z,b1.w};
            #pragma unroll
            for (int i = 0; i < 8; ++i)
                #pragma unroll
                for (int j = 0; j < 8; ++j) acc[i][j] += av[i] * bv[j];
        }
        __syncthreads();
    }

    float bias[8];
    #pragma unroll
    for (int j = 0; j < 8; ++j) { const int col = j0 + tn0 + j; bias[j] = bi[col] + bh[col]; }

    float* __restrict__ xpd = xp + (size_t)dir * T_LEN * GDIM;
    #pragma unroll
    for (int i = 0; i < 8; ++i) {
        const int tr = t0 + tm0 + i;
        float4 o0, o1;
        o0.x = acc[i][0] + bias[0]; o0.y = acc[i][1] + bias[1];
        o0.z = acc[i][2] + bias[2]; o0.w = acc[i][3] + bias[3];
        o1.x = acc[i][4] + bias[4]; o1.y = acc[i][5] + bias[5];
        o1.z = acc[i][6] + bias[6]; o1.w = acc[i][7] + bias[7];
        *(float4*)&xpd[(size_t)tr * GDIM + j0 + tn0]     = o0;
        *(float4*)&xpd[(size_t)tr * GDIM + j0 + tn0 + 4] = o1;
    }
}

// ============================================================================
// Kernel 2: cooperative persistent bidirectional LSTM scan.
// 256 blocks x 256 threads, 1 block/CU (131KB LDS weights).
// Block b: dir = b>>7, owns 8 hidden units (32 gate rows) -> w_hh slice in LDS.
// Per step: 32 dots of 1024 (each thread: 4 rows x 32 k-elems), shfl reduce,
// cell update on 8 threads, publish h via 64-bit (tag|value) atomic slots,
// poll peers' slots (single L3 round trip), restage h into LDS.
// Hang-proofing: bounded poll budget per thread; on exhaustion, proceed with
// stale data (wrong output, but no GPU hang -> diagnosable signature).
// ============================================================================
__global__ __launch_bounds__(256, 1)
void lstm_scan(const float* __restrict__ xp,
               const float* __restrict__ h0,
               const float* __restrict__ c0,
               const float* __restrict__ whh_f,
               const float* __restrict__ whh_b,
               float* __restrict__ hist,
               unsigned long long* __restrict__ slots)
{
    __shared__ float wsl[32][1024];   // 131072 B
    __shared__ float hbuf[1024];      //   4096 B
    __shared__ float gsh[32];

    const int tid = threadIdx.x;
    const int b   = blockIdx.x;
    const int dir = b >> 7;
    const int bi  = b & 127;
    const int u0  = bi * 8;
    const int rg  = tid >> 5;   // 0..7  (row group: 4 rows)
    const int kc  = tid & 31;   // 0..31 (k chunk: 32 elems, strided)
    const int lrb = rg * 4;

    const float* __restrict__ whh = dir ? whh_b : whh_f;
    const size_t xpbase = (size_t)dir * T_LEN * GDIM;

    // stage w_hh slice: local row lr = gate*8 + u  ->  global row gate*1024 + u0 + u
    for (int lr = 0; lr < 32; ++lr) {
        const int grow = ((lr >> 3) << 10) + u0 + (lr & 7);
        *(float4*)&wsl[lr][tid * 4] = *(const float4*)&whh[(size_t)grow * H2DIM + tid * 4];
    }
    *(float4*)&hbuf[tid * 4] = *(const float4*)&h0[dir * H2DIM + tid * 4];
    float creg = 0.f;
    if (tid < 8) creg = c0[dir * H2DIM + u0 + tid];

    int grows[4];
    #pragma unroll
    for (int j = 0; j < 4; ++j) {
        const int lr = lrb + j;
        grows[j] = ((lr >> 3) << 10) + u0 + (lr & 7);
    }
    float xpc[4] = {0.f, 0.f, 0.f, 0.f};
    if (kc == 0) {
        #pragma unroll
        for (int j = 0; j < 4; ++j) xpc[j] = xp[xpbase + grows[j]];
    }
    __syncthreads();

    int budget = 4000000;   // total poll iterations per thread across all steps

    for (int t = 0; t < T_LEN; ++t) {
        // prefetch next step's xp (hides HBM latency under this step's compute)
        float xpn[4] = {0.f, 0.f, 0.f, 0.f};
        const int tnx = (t + 1 < T_LEN) ? (t + 1) : t;
        if (kc == 0) {
            #pragma unroll
            for (int j = 0; j < 4; ++j) xpn[j] = xp[xpbase + (size_t)tnx * GDIM + grows[j]];
        }

        // partial dots: 4 rows x 32 k-elems (contiguous b128 reads, conflict-free)
        float p0 = 0.f, p1 = 0.f, p2 = 0.f, p3 = 0.f;
        #pragma unroll
        for (int s = 0; s < 8; ++s) {
            const int ko = s * 128 + kc * 4;
            const float4 hv = *(const float4*)&hbuf[ko];
            const float4 w0 = *(const float4*)&wsl[lrb + 0][ko];
            const float4 w1 = *(const float4*)&wsl[lrb + 1][ko];
            const float4 w2 = *(const float4*)&wsl[lrb + 2][ko];
            const float4 w3 = *(const float4*)&wsl[lrb + 3][ko];
            p0 += w0.x*hv.x + w0.y*hv.y + w0.z*hv.z + w0.w*hv.w;
            p1 += w1.x*hv.x + w1.y*hv.y + w1.z*hv.z + w1.w*hv.w;
            p2 += w2.x*hv.x + w2.y*hv.y + w2.z*hv.z + w2.w*hv.w;
            p3 += w3.x*hv.x + w3.y*hv.y + w3.z*hv.z + w3.w*hv.w;
        }
        // reduce over the 32 kc lanes (butterfly stays within each 32-lane half)
        #pragma unroll
        for (int m = 16; m >= 1; m >>= 1) {
            p0 += __shfl_xor(p0, m);
            p1 += __shfl_xor(p1, m);
            p2 += __shfl_xor(p2, m);
            p3 += __shfl_xor(p3, m);
        }
        if (kc == 0) {
            gsh[lrb + 0] = p0 + xpc[0];
            gsh[lrb + 1] = p1 + xpc[1];
            gsh[lrb + 2] = p2 + xpc[2];
            gsh[lrb + 3] = p3 + xpc[3];
        }
        __syncthreads();

        // LSTM cell on 8 threads (one per hidden unit)
        if (tid < 8) {
            const float gi = gsh[tid];
            const float gf = gsh[8 + tid];
            const float gg = gsh[16 + tid];
            const float go = gsh[24 + tid];
            const float c  = sigm(gf) * creg + sigm(gi) * tanhf(gg);
            const float h  = sigm(go) * tanhf(c);
            creg = c;
            const int tg = dir ? (T_LEN - 1 - t) : t;
            hist[(size_t)tg * 2048 + dir * H2DIM + u0 + tid] = h;
            const unsigned long long pack =
                ((unsigned long long)(unsigned)(t + 1) << 32) |
                (unsigned long long)__float_as_uint(h);
            __hip_atomic_store(&slots[((size_t)((t + 1) & 1) * 2 + dir) * H2DIM + u0 + tid],
                               pack, __ATOMIC_RELAXED, __HIP_MEMORY_SCOPE_AGENT);
        }

        // poll peers' h slots for tag t+1 (4 independent loads per sweep -> ILP)
        if (t + 1 < T_LEN) {
            const unsigned want = (unsigned)(t + 1);
            unsigned long long* sb = &slots[((size_t)((t + 1) & 1) * 2 + dir) * H2DIM + tid * 4];
            unsigned long long v0 = 0, v1 = 0, v2 = 0, v3 = 0;
            bool g0 = false, g1 = false, g2 = false, g3 = false;
            for (;;) {
                if (!g0) v0 = __hip_atomic_load(&sb[0], __ATOMIC_RELAXED, __HIP_MEMORY_SCOPE_AGENT);
                if (!g1) v1 = __hip_atomic_load(&sb[1], __ATOMIC_RELAXED, __HIP_MEMORY_SCOPE_AGENT);
                if (!g2) v2 = __hip_atomic_load(&sb[2], __ATOMIC_RELAXED, __HIP_MEMORY_SCOPE_AGENT);
                if (!g3) v3 = __hip_atomic_load(&sb[3], __ATOMIC_RELAXED, __HIP_MEMORY_SCOPE_AGENT);
                g0 = g0 || ((unsigned)(v0 >> 32) == want);
                g1 = g1 || ((unsigned)(v1 >> 32) == want);
                g2 = g2 || ((unsigned)(v2 >> 32) == want);
                g3 = g3 || ((unsigned)(v3 >> 32) == want);
                if (g0 && g1 && g2 && g3) break;
                if (--budget <= 0) break;                // hang-proof: bail, wrong-but-finite
                __builtin_amdgcn_s_sleep(1);             // backoff: reduce L3 atomic pressure
            }
            float4 hv;
            hv.x = __uint_as_float((unsigned)v0);
            hv.y = __uint_as_float((unsigned)v1);
            hv.z = __uint_as_float((unsigned)v2);
            hv.w = __uint_as_float((unsigned)v3);
            *(float4*)&hbuf[tid * 4] = hv;
        }
        __syncthreads();
        if (kc == 0) { xpc[0] = xpn[0]; xpc[1] = xpn[1]; xpc[2] = xpn[2]; xpc[3] = xpn[3]; }
    }
}

// ============================================================================
// Kernel 3: feats[t][n] = dot(hist[t], w_tag[n]) + b_tag[n]
// ============================================================================
__global__ __launch_bounds__(256)
void feats_kernel(const float* __restrict__ hist,
                  const float* __restrict__ w_tag,
                  const float* __restrict__ b_tag,
                  float* __restrict__ feats)
{
    const int t = blockIdx.x;
    const int tid = threadIdx.x;
    const float* __restrict__ hrow = hist + (size_t)t * 2048 + tid * 8;
    const float4 ha = *(const float4*)&hrow[0];
    const float4 hb = *(const float4*)&hrow[4];
    float p[4];
    #pragma unroll
    for (int n = 0; n < 4; ++n) {
        const float* __restrict__ wr = w_tag + n * 2048 + tid * 8;
        const float4 wa = *(const float4*)&wr[0];
        const float4 wb = *(const float4*)&wr[4];
        p[n] = ha.x*wa.x + ha.y*wa.y + ha.z*wa.z + ha.w*wa.w
             + hb.x*wb.x + hb.y*wb.y + hb.z*wb.z + hb.w*wb.w;
    }
    #pragma unroll
    for (int m = 32; m >= 1; m >>= 1) {
        #pragma unroll
        for (int n = 0; n < 4; ++n) p[n] += __shfl_down(p[n], m);
    }
    __shared__ float red[4][4];
    const int wv = tid >> 6;
    if ((tid & 63) == 0) {
        #pragma unroll
        for (int n = 0; n < 4; ++n) red[n][wv] = p[n];
    }
    __syncthreads();
    if (tid < 4)
        feats[(size_t)t * 4 + tid] = red[tid][0] + red[tid][1] + red[tid][2] + red[tid][3] + b_tag[tid];
}

// ============================================================================
// Kernel 4: Viterbi (4 tags): forward DP + backtrace, op-order matches ref.
// ============================================================================
__global__ __launch_bounds__(256)
void viterbi_kernel(const float* __restrict__ feats,
                    const float* __restrict__ trans,
                    float* __restrict__ out)
{
    __shared__ float fsh[T_LEN * 4];   // 64 KB
    __shared__ unsigned bp[T_LEN];     // 16 KB
    const int tid = threadIdx.x;
    for (int i = tid; i < T_LEN; i += 256)
        *(float4*)&fsh[i * 4] = *(const float4*)&feats[(size_t)i * 4];
    __syncthreads();
    if (tid == 0) {
        float tr[16];
        #pragma unroll
        for (int i = 0; i < 16; ++i) tr[i] = trans[i];
        float fv[4] = {NEGV, NEGV, NEGV, NEGV};
        fv[START_TAG] = 0.0f;
        for (int t = 0; t < T_LEN; ++t) {
            float nf[4]; unsigned pb = 0;
            #pragma unroll
            for (int n = 0; n < 4; ++n) {
                float m = fv[0] + tr[n * 4 + 0]; int bsel = 0;
                #pragma unroll
                for (int p = 1; p < 4; ++p) {
                    const float s = fv[p] + tr[n * 4 + p];
                    if (s > m) { m = s; bsel = p; }
                }
                nf[n] = m + fsh[t * 4 + n];
                pb |= (unsigned)bsel << (8 * n);
            }
            bp[t] = pb;
            fv[0] = nf[0]; fv[1] = nf[1]; fv[2] = nf[2]; fv[3] = nf[3];
        }
        float bm = fv[0] + tr[STOP_TAG * 4 + 0]; int best = 0;
        #pragma unroll
        for (int p = 1; p < 4; ++p) {
            const float s = fv[p] + tr[STOP_TAG * 4 + p];
            if (s > bm) { bm = s; best = p; }
        }
        out[0] = bm;
        int cur = best;
        for (int t = T_LEN - 1; t >= 0; --t) {
            out[1 + t] = (float)cur;
            cur = (int)((bp[t] >> (8 * cur)) & 0xffu);
        }
    }
}

// ============================================================================
extern "C" void kernel_launch(void* const* d_in, const int* in_sizes, int n_in,
                              void* d_out, int out_size, void* d_ws, size_t ws_size,
                              hipStream_t stream) {
    const float* x      = (const float*)d_in[0];
    const float* h0     = (const float*)d_in[1];
    const float* c0     = (const float*)d_in[2];
    const float* w_ih_f = (const float*)d_in[3];
    const float* w_hh_f = (const float*)d_in[4];
    const float* b_ih_f = (const float*)d_in[5];
    const float* b_hh_f = (const float*)d_in[6];
    const float* w_ih_b = (const float*)d_in[7];
    const float* w_hh_b = (const float*)d_in[8];
    const float* b_ih_b = (const float*)d_in[9];
    const float* b_hh_b = (const float*)d_in[10];
    const float* w_tag  = (const float*)d_in[11];
    const float* b_tag  = (const float*)d_in[12];
    const float* trans  = (const float*)d_in[13];
    float* out = (float*)d_out;

    if (ws_size < WS_NEED) return;   // signature: output stays poisoned (absmax == ref max)

    char* ws = (char*)d_ws;
    float* xp    = (float*)(ws + XP_OFF);
    float* hist  = (float*)(ws + HIST_OFF);
    float* feats = (float*)(ws + FEATS_OFF);
    unsigned long long* slots = (unsigned long long*)(ws + SLOTS_OFF);

    hipMemsetAsync(slots, 0, SLOTS_BYTES, stream);

    dim3 ggrid(32, 32, 2);
    xp_gemm<<<ggrid, 256, 0, stream>>>(x, w_ih_f, w_ih_b, b_ih_f, b_hh_f, b_ih_b, b_hh_b, xp);

    void* ka[] = { (void*)&xp, (void*)&h0, (void*)&c0, (void*)&w_hh_f, (void*)&w_hh_b,
                   (void*)&hist, (void*)&slots };
    hipLaunchCooperativeKernel((void*)lstm_scan, dim3(256), dim3(256), ka, 0, stream);

    feats_kernel<<<T_LEN, 256, 0, stream>>>(hist, w_tag, b_tag, feats);
    viterbi_kernel<<<1, 256, 0, stream>>>(feats, trans, out);
}